// Round 1
// baseline (1150.815 us; speedup 1.0000x reference)
//
#include <hip/hip_runtime.h>
#include <hip/hip_bf16.h>
#include <stdint.h>

typedef float f32x4 __attribute__((ext_vector_type(4)));
typedef __bf16 bf16x8 __attribute__((ext_vector_type(8)));
typedef unsigned short ushortx8 __attribute__((ext_vector_type(8)));
typedef int i32x4 __attribute__((ext_vector_type(4)));

#define BM 128
#define BN 128
#define BK 32

// ---------- fp32 -> bf16 (RTNE) ----------
__device__ __forceinline__ unsigned short f2bf(float f) {
    unsigned u = __builtin_bit_cast(unsigned, f);
    u += 0x7FFFu + ((u >> 16) & 1u);
    return (unsigned short)(u >> 16);
}

__global__ __launch_bounds__(256) void cvt_f32_bf16_kernel(
        const float* __restrict__ in, unsigned short* __restrict__ out, long n) {
    long base = ((long)blockIdx.x * 256 + threadIdx.x) * 8;
    long stride = (long)gridDim.x * 256 * 8;
    for (long i = base; i < n; i += stride) {
        f32x4 v0 = *(const f32x4*)(in + i);
        f32x4 v1 = *(const f32x4*)(in + i + 4);
        ushortx8 o;
        o[0] = f2bf(v0[0]); o[1] = f2bf(v0[1]); o[2] = f2bf(v0[2]); o[3] = f2bf(v0[3]);
        o[4] = f2bf(v1[0]); o[5] = f2bf(v1[1]); o[6] = f2bf(v1[2]); o[7] = f2bf(v1[3]);
        *(ushortx8*)(out + i) = o;
    }
}

__global__ __launch_bounds__(256) void cvt_i32_bf16_kernel(
        const int* __restrict__ in, unsigned short* __restrict__ out, long n) {
    long base = ((long)blockIdx.x * 256 + threadIdx.x) * 8;
    long stride = (long)gridDim.x * 256 * 8;
    for (long i = base; i < n; i += stride) {
        i32x4 v0 = *(const i32x4*)(in + i);
        i32x4 v1 = *(const i32x4*)(in + i + 4);
        ushortx8 o;
        o[0] = f2bf((float)v0[0]); o[1] = f2bf((float)v0[1]);
        o[2] = f2bf((float)v0[2]); o[3] = f2bf((float)v0[3]);
        o[4] = f2bf((float)v1[0]); o[5] = f2bf((float)v1[1]);
        o[6] = f2bf((float)v1[2]); o[7] = f2bf((float)v1[3]);
        *(ushortx8*)(out + i) = o;
    }
}

// ---------- async global -> LDS, 16B per lane ----------
__device__ __forceinline__ void gload_lds16(const void* g, void* l) {
    __builtin_amdgcn_global_load_lds(
        (const __attribute__((address_space(1))) unsigned int*)g,
        (__attribute__((address_space(3))) unsigned int*)l,
        16, 0, 0);
}

// ---------- m97-structure bf16 GEMM: C = A(MxK) * W(NxK)^T, fused scale+bias ----------
__global__ __launch_bounds__(256, 3) void gemm_bf16_kernel(
        const unsigned short* __restrict__ A,   // [M][K] bf16 bits
        const unsigned short* __restrict__ W,   // [N][K] bf16 bits
        const float* __restrict__ scales,       // [N]
        const float* __restrict__ bias,         // [N]
        float* __restrict__ C,                  // [M][N]
        int M, int N, int K) {
    __shared__ unsigned short As[BM * BK];   // 8 KiB
    __shared__ unsigned short Ws[BN * BK];   // 8 KiB

    const int tid  = threadIdx.x;
    const int wave = tid >> 6;
    const int lane = tid & 63;

    // XCD-aware swizzle (bijective when nwg % 8 == 0)
    const int nwg = gridDim.x;
    int bid = blockIdx.x;
    int swz = ((nwg & 7) == 0) ? ((bid & 7) * (nwg >> 3) + (bid >> 3)) : bid;
    const int tiles_n = N / BN;
    const int tm = swz / tiles_n;
    const int tn = swz % tiles_n;

    const int wr = wave >> 1;   // 0..1: wave row in 2x2 wave grid
    const int wc = wave & 1;    // 0..1

    const int fr = lane & 15;   // fragment row/col
    const int fq = lane >> 4;   // 0..3: k-group (A/B), row-group (C/D)

    // staging decomposition: per issue, wave covers 16 rows x full BK
    const int srow = lane >> 2;        // 0..15
    const int scol = (lane & 3) * 8;   // element offset along K
    const long rowA0 = (long)tm * BM;
    const long rowW0 = (long)tn * BN;

    f32x4 acc[4][4] = {};

    const int nk = K / BK;
    for (int kt = 0; kt < nk; ++kt) {
        __syncthreads();   // previous compute done reading LDS
        const int k0 = kt * BK;
#pragma unroll
        for (int i = 0; i < 2; ++i) {
            const int r = i * 64 + wave * 16 + srow;
            const size_t loff = (size_t)(i * 2048 + wave * 512);  // elements (x2B = bytes/issue chunk)
            gload_lds16(A + (rowA0 + r) * (long)K + k0 + scol, (void*)(As + loff));
            gload_lds16(W + (rowW0 + r) * (long)K + k0 + scol, (void*)(Ws + loff));
        }
        __syncthreads();   // implies vmcnt(0) drain: LDS tile ready

        bf16x8 af[4], wf[4];
#pragma unroll
        for (int m = 0; m < 4; ++m)
            af[m] = *(const bf16x8*)(As + (wr * 64 + m * 16 + fr) * BK + fq * 8);
#pragma unroll
        for (int n = 0; n < 4; ++n)
            wf[n] = *(const bf16x8*)(Ws + (wc * 64 + n * 16 + fr) * BK + fq * 8);
#pragma unroll
        for (int m = 0; m < 4; ++m)
#pragma unroll
            for (int n = 0; n < 4; ++n)
                acc[m][n] = __builtin_amdgcn_mfma_f32_16x16x32_bf16(af[m], wf[n], acc[m][n], 0, 0, 0);
    }

    // epilogue: out = acc * scales[col] + bias[col]
#pragma unroll
    for (int n = 0; n < 4; ++n) {
        const int col = tn * BN + wc * 64 + n * 16 + fr;
        const float s = scales[col];
        const float b = bias[col];
#pragma unroll
        for (int m = 0; m < 4; ++m) {
            const int row0 = tm * BM + wr * 64 + m * 16 + fq * 4;
#pragma unroll
            for (int j = 0; j < 4; ++j)
                C[(long)(row0 + j) * N + col] = acc[m][n][j] * s + b;
        }
    }
}

// ---------- fallback: plain fp32 register-tiled GEMM (only if ws too small) ----------
__global__ __launch_bounds__(256) void gemm_fallback_kernel(
        const float* __restrict__ A, const int* __restrict__ W,
        const float* __restrict__ scales, const float* __restrict__ bias,
        float* __restrict__ C, int M, int N, int K) {
    __shared__ float As[64][16];
    __shared__ float Ws[64][16];
    const int tiles_n = N / 64;
    const int tm = blockIdx.x / tiles_n;
    const int tn = blockIdx.x % tiles_n;
    const int tid = threadIdx.x;
    const int tx = tid & 15, ty = tid >> 4;
    float acc[4][4] = {};
    for (int k0 = 0; k0 < K; k0 += 16) {
        __syncthreads();
#pragma unroll
        for (int i = 0; i < 4; ++i) {
            const int idx = tid + i * 256;
            const int r = idx >> 4, c = idx & 15;
            As[r][c] = A[(long)(tm * 64 + r) * K + k0 + c];
            Ws[r][c] = (float)W[(long)(tn * 64 + r) * K + k0 + c];
        }
        __syncthreads();
#pragma unroll
        for (int kk = 0; kk < 16; ++kk) {
            float a[4], w[4];
#pragma unroll
            for (int r = 0; r < 4; ++r) a[r] = As[ty * 4 + r][kk];
#pragma unroll
            for (int c = 0; c < 4; ++c) w[c] = Ws[tx * 4 + c][kk];
#pragma unroll
            for (int r = 0; r < 4; ++r)
#pragma unroll
                for (int c = 0; c < 4; ++c) acc[r][c] += a[r] * w[c];
        }
    }
#pragma unroll
    for (int r = 0; r < 4; ++r)
#pragma unroll
        for (int c = 0; c < 4; ++c) {
            const int col = tn * 64 + tx * 4 + c;
            C[(long)(tm * 64 + ty * 4 + r) * N + col] = acc[r][c] * scales[col] + bias[col];
        }
}

extern "C" void kernel_launch(void* const* d_in, const int* in_sizes, int n_in,
                              void* d_out, int out_size, void* d_ws, size_t ws_size,
                              hipStream_t stream) {
    const float* A32    = (const float*)d_in[0];
    const int*   Wq     = (const int*)d_in[1];
    const float* scales = (const float*)d_in[2];
    const float* bias   = (const float*)d_in[3];
    float* C = (float*)d_out;

    const long aElems = in_sizes[0];        // M*K
    const long wElems = in_sizes[1];        // N*K
    const int  N = in_sizes[2];
    const int  K = (int)(wElems / N);
    const int  M = (int)(aElems / K);

    const size_t need = (size_t)(aElems + wElems) * 2;
    const bool divisible = (M % BM == 0) && (N % BN == 0) && (K % BK == 0);

    if (ws_size >= need && divisible) {
        unsigned short* Abf = (unsigned short*)d_ws;
        unsigned short* Wbf = Abf + aElems;
        cvt_f32_bf16_kernel<<<2048, 256, 0, stream>>>(A32, Abf, aElems);
        cvt_i32_bf16_kernel<<<2048, 256, 0, stream>>>(Wq, Wbf, wElems);
        const int nwg = (M / BM) * (N / BN);
        gemm_bf16_kernel<<<nwg, 256, 0, stream>>>(Abf, Wbf, scales, bias, C, M, N, K);
    } else {
        const int nwg = (M / 64) * (N / 64);
        gemm_fallback_kernel<<<nwg, 256, 0, stream>>>(A32, Wq, scales, bias, C, M, N, K);
    }
}

// Round 2
// 748.100 us; speedup vs baseline: 1.5383x; 1.5383x over previous
//
#include <hip/hip_runtime.h>
#include <hip/hip_bf16.h>
#include <stdint.h>

typedef float f32x4 __attribute__((ext_vector_type(4)));
typedef __bf16 bf16x8 __attribute__((ext_vector_type(8)));
typedef unsigned short ushortx8 __attribute__((ext_vector_type(8)));
typedef int i32x4 __attribute__((ext_vector_type(4)));

// ---------------- fp32/i32 -> bf16 conversion ----------------
__device__ __forceinline__ unsigned short f2bf(float f) {
    unsigned u = __builtin_bit_cast(unsigned, f);
    u += 0x7FFFu + ((u >> 16) & 1u);
    return (unsigned short)(u >> 16);
}

__global__ __launch_bounds__(256) void cvt_f32_bf16_kernel(
        const float* __restrict__ in, unsigned short* __restrict__ out, long n) {
    long base = ((long)blockIdx.x * 256 + threadIdx.x) * 8;
    long stride = (long)gridDim.x * 256 * 8;
    for (long i = base; i < n; i += stride) {
        f32x4 v0 = *(const f32x4*)(in + i);
        f32x4 v1 = *(const f32x4*)(in + i + 4);
        ushortx8 o;
        o[0] = f2bf(v0[0]); o[1] = f2bf(v0[1]); o[2] = f2bf(v0[2]); o[3] = f2bf(v0[3]);
        o[4] = f2bf(v1[0]); o[5] = f2bf(v1[1]); o[6] = f2bf(v1[2]); o[7] = f2bf(v1[3]);
        *(ushortx8*)(out + i) = o;
    }
}

__global__ __launch_bounds__(256) void cvt_i32_bf16_kernel(
        const int* __restrict__ in, unsigned short* __restrict__ out, long n) {
    long base = ((long)blockIdx.x * 256 + threadIdx.x) * 8;
    long stride = (long)gridDim.x * 256 * 8;
    for (long i = base; i < n; i += stride) {
        i32x4 v0 = *(const i32x4*)(in + i);
        i32x4 v1 = *(const i32x4*)(in + i + 4);
        ushortx8 o;
        o[0] = f2bf((float)v0[0]); o[1] = f2bf((float)v0[1]);
        o[2] = f2bf((float)v0[2]); o[3] = f2bf((float)v0[3]);
        o[4] = f2bf((float)v1[0]); o[5] = f2bf((float)v1[1]);
        o[6] = f2bf((float)v1[2]); o[7] = f2bf((float)v1[3]);
        *(ushortx8*)(out + i) = o;
    }
}

// ---------------- async global -> LDS (16B/lane, wave-uniform LDS base) ----------------
__device__ __forceinline__ void gload_lds16(const void* g, void* l) {
    __builtin_amdgcn_global_load_lds(
        (const __attribute__((address_space(1))) unsigned int*)g,
        (__attribute__((address_space(3))) unsigned int*)l,
        16, 0, 0);
}

// =====================================================================
// 256x256 8-phase bf16 GEMM (m201-style), C = A[MxK] * W[NxK]^T * s + b
// 512 thr = 8 waves (2M x 4N, strided fragment ownership).
// LDS 128 KiB: region(buf, op, half) = buf*32768 + op*16384 + half*8192 elems,
// each region = 128 rows x 64 cols bf16, row-major, 128 B rows,
// XOR-swizzled: LDS[row][cb] holds global colbyte cb ^ ((row&7)<<4).
// =====================================================================

// stage one half-tile (128 rows x 64 cols): 2 issues x (512 lanes x 16 B)
__device__ __forceinline__ void stage_half(const unsigned short* __restrict__ G,
        long grow0, int K, int kcol0, unsigned short* lds_region, int tid) {
    const int r   = tid >> 3;        // 0..63 row within 64-row issue chunk
    const int c8  = tid & 7;         // 16B slot within row
    const int wid = tid >> 6;
#pragma unroll
    for (int j = 0; j < 2; ++j) {
        const int lrow = j * 64 + r;
        const int gcol = kcol0 + ((c8 ^ (lrow & 7)) << 3);   // pre-swizzled source
        gload_lds16(G + (grow0 + lrow) * (long)K + gcol,
                    lds_region + j * 4096 + wid * 512);      // HW adds lane*16B
    }
}

template<int BUF, int MH>
__device__ __forceinline__ void readA(const unsigned short* smem, bf16x8 (&fa)[4][2],
                                      int wr, int fr, int fq) {
    const unsigned short* rg = smem + BUF * 32768 + MH * 8192;
#pragma unroll
    for (int ml = 0; ml < 4; ++ml)
#pragma unroll
        for (int kk = 0; kk < 2; ++kk) {
            const int lrow = wr * 16 + ml * 32 + fr;
            const int cb = (((kk * 4 + fq) << 4)) ^ ((lrow & 7) << 4);
            fa[ml][kk] = *(const bf16x8*)(rg + lrow * 64 + (cb >> 1));
        }
}

template<int BUF, int NH>
__device__ __forceinline__ void readB(const unsigned short* smem, bf16x8 (&fb)[2][2],
                                      int wc, int fr, int fq) {
    const unsigned short* rg = smem + BUF * 32768 + 16384 + NH * 8192;
#pragma unroll
    for (int nl = 0; nl < 2; ++nl)
#pragma unroll
        for (int kk = 0; kk < 2; ++kk) {
            const int lrow = wc * 16 + nl * 64 + fr;
            const int cb = (((kk * 4 + fq) << 4)) ^ ((lrow & 7) << 4);
            fb[nl][kk] = *(const bf16x8*)(rg + lrow * 64 + (cb >> 1));
        }
}

template<int MH, int NH>
__device__ __forceinline__ void mfmas(f32x4 (&acc)[8][4],
                                      const bf16x8 (&fa)[4][2], const bf16x8 (&fb)[2][2]) {
#pragma unroll
    for (int ml = 0; ml < 4; ++ml)
#pragma unroll
        for (int nl = 0; nl < 2; ++nl)
#pragma unroll
            for (int kk = 0; kk < 2; ++kk)
                acc[MH * 4 + ml][NH * 2 + nl] = __builtin_amdgcn_mfma_f32_16x16x32_bf16(
                    fa[ml][kk], fb[nl][kk], acc[MH * 4 + ml][NH * 2 + nl], 0, 0, 0);
}

#define SYNC_PRE()  { __builtin_amdgcn_s_barrier();                              \
                      asm volatile("s_waitcnt lgkmcnt(0)" ::: "memory");         \
                      __builtin_amdgcn_sched_barrier(0);                         \
                      __builtin_amdgcn_s_setprio(1); }
#define POST()      { __builtin_amdgcn_s_setprio(0); __builtin_amdgcn_s_barrier(); }
#define POST_V6()   { __builtin_amdgcn_s_setprio(0);                             \
                      asm volatile("s_waitcnt vmcnt(6)" ::: "memory");           \
                      __builtin_amdgcn_s_barrier(); }
#define POST_V0()   { __builtin_amdgcn_s_setprio(0);                             \
                      asm volatile("s_waitcnt vmcnt(0)" ::: "memory");           \
                      __builtin_amdgcn_s_barrier(); }

__global__ __launch_bounds__(512, 1) void gemm_bf16_8phase(
        const unsigned short* __restrict__ A,   // [M][K] bf16 bits
        const unsigned short* __restrict__ W,   // [N][K] bf16 bits
        const float* __restrict__ scales,
        const float* __restrict__ bias,
        float* __restrict__ C,                  // [M][N]
        int M, int N, int K) {
    extern __shared__ unsigned short smem[];    // 65536 elems = 128 KiB

    const int tid  = threadIdx.x;
    const int wid  = tid >> 6;
    const int lane = tid & 63;
    const int wr = wid >> 2;     // 0..1
    const int wc = wid & 3;      // 0..3
    const int fr = lane & 15;
    const int fq = lane >> 4;

    const int nwg = gridDim.x;
    const int bid = blockIdx.x;
    const int swz = ((nwg & 7) == 0) ? ((bid & 7) * (nwg >> 3) + (bid >> 3)) : bid;
    const int tiles_n = N >> 8;
    const int tm = swz / tiles_n;
    const int tn = swz % tiles_n;
    const long arow = (long)tm * 256;
    const long brow = (long)tn * 256;

    f32x4 acc[8][4] = {};
    bf16x8 fa[4][2], fb0[2][2], fb1[2][2];

    const int NT = K >> 6;       // K-tiles of 64; NT even, >= 2

#define STA(kt, h) stage_half(A, arow + (h) * 128, K, (kt) * 64, \
                              smem + ((kt) & 1) * 32768 + (h) * 8192, tid)
#define STB(kt, h) stage_half(W, brow + (h) * 128, K, (kt) * 64, \
                              smem + ((kt) & 1) * 32768 + 16384 + (h) * 8192, tid)

    // ---- prologue: 7 half-tile stages (tile0 full + tile1 minus A.h1)
    STA(0, 0); STB(0, 0); STA(0, 1); STB(0, 1);
    STA(1, 0); STB(1, 0); STB(1, 1);
    asm volatile("s_waitcnt vmcnt(6)" ::: "memory");   // tile0's 4 stages landed
    __builtin_amdgcn_s_barrier();

    // ---- main loop: iteration consumes tiles (2i)->buf0, (2i+1)->buf1
    for (int i = 0; i < (NT >> 1) - 1; ++i) {
        const int b = 2 * i + 1, c = 2 * i + 2, d = 2 * i + 3;
        // ph1 (mh0,nh0 of buf0)
        readA<0, 0>(smem, fa, wr, fr, fq); readB<0, 0>(smem, fb0, wc, fr, fq); STA(b, 1);
        SYNC_PRE(); mfmas<0, 0>(acc, fa, fb0); POST();
        // ph2 (mh0,nh1)
        readB<0, 1>(smem, fb1, wc, fr, fq); STA(c, 0);
        SYNC_PRE(); mfmas<0, 1>(acc, fa, fb1); POST();
        // ph3 (mh1,nh0)
        readA<0, 1>(smem, fa, wr, fr, fq); STB(c, 0);
        SYNC_PRE(); mfmas<1, 0>(acc, fa, fb0); POST();
        // ph4 (mh1,nh1) + fence
        STB(c, 1);
        SYNC_PRE(); mfmas<1, 1>(acc, fa, fb1); POST_V6();
        // ph5 (mh0,nh0 of buf1)
        readA<1, 0>(smem, fa, wr, fr, fq); readB<1, 0>(smem, fb0, wc, fr, fq); STA(c, 1);
        SYNC_PRE(); mfmas<0, 0>(acc, fa, fb0); POST();
        // ph6
        readB<1, 1>(smem, fb1, wc, fr, fq); STA(d, 0);
        SYNC_PRE(); mfmas<0, 1>(acc, fa, fb1); POST();
        // ph7
        readA<1, 1>(smem, fa, wr, fr, fq); STB(d, 0);
        SYNC_PRE(); mfmas<1, 0>(acc, fa, fb0); POST();
        // ph8 + fence
        STB(d, 1);
        SYNC_PRE(); mfmas<1, 1>(acc, fa, fb1); POST_V6();
    }

    // ---- epilogue iteration: tiles NT-2 (buf0), NT-1 (buf1); no prefetch
    readA<0, 0>(smem, fa, wr, fr, fq); readB<0, 0>(smem, fb0, wc, fr, fq); STA(NT - 1, 1);
    SYNC_PRE(); mfmas<0, 0>(acc, fa, fb0); POST();
    readB<0, 1>(smem, fb1, wc, fr, fq);
    SYNC_PRE(); mfmas<0, 1>(acc, fa, fb1); POST();
    readA<0, 1>(smem, fa, wr, fr, fq);
    SYNC_PRE(); mfmas<1, 0>(acc, fa, fb0); POST();
    SYNC_PRE(); mfmas<1, 1>(acc, fa, fb1); POST_V0();   // drain: tile NT-1 fully landed
    readA<1, 0>(smem, fa, wr, fr, fq); readB<1, 0>(smem, fb0, wc, fr, fq);
    SYNC_PRE(); mfmas<0, 0>(acc, fa, fb0); POST();
    readB<1, 1>(smem, fb1, wc, fr, fq);
    SYNC_PRE(); mfmas<0, 1>(acc, fa, fb1); POST();
    readA<1, 1>(smem, fa, wr, fr, fq);
    SYNC_PRE(); mfmas<1, 0>(acc, fa, fb0); POST();
    SYNC_PRE(); mfmas<1, 1>(acc, fa, fb1);
    __builtin_amdgcn_s_setprio(0);

#undef STA
#undef STB

    // ---- C write: out = acc * scales[col] + bias[col]
#pragma unroll
    for (int n = 0; n < 4; ++n) {
        const int col = tn * 256 + wc * 16 + n * 64 + fr;
        const float s = scales[col];
        const float bb = bias[col];
#pragma unroll
        for (int mh = 0; mh < 2; ++mh)
#pragma unroll
            for (int ml = 0; ml < 4; ++ml) {
                const long row0 = arow + wr * 16 + mh * 128 + ml * 32 + fq * 4;
#pragma unroll
                for (int j = 0; j < 4; ++j)
                    C[(row0 + j) * (long)N + col] = acc[mh * 4 + ml][n][j] * s + bb;
            }
    }
}

// =====================================================================
// fallback #1: verified 128^2 m97-structure kernel (round-1, 687 TF)
// =====================================================================
__global__ __launch_bounds__(256, 3) void gemm_bf16_128(
        const unsigned short* __restrict__ A, const unsigned short* __restrict__ W,
        const float* __restrict__ scales, const float* __restrict__ bias,
        float* __restrict__ C, int M, int N, int K) {
    __shared__ unsigned short As[128 * 32];
    __shared__ unsigned short Ws[128 * 32];
    const int tid = threadIdx.x, wave = tid >> 6, lane = tid & 63;
    const int nwg = gridDim.x;
    int bid = blockIdx.x;
    int swz = ((nwg & 7) == 0) ? ((bid & 7) * (nwg >> 3) + (bid >> 3)) : bid;
    const int tiles_n = N / 128;
    const int tm = swz / tiles_n, tn = swz % tiles_n;
    const int wr = wave >> 1, wc = wave & 1;
    const int fr = lane & 15, fq = lane >> 4;
    const int srow = lane >> 2, scol = (lane & 3) * 8;
    const long rowA0 = (long)tm * 128, rowW0 = (long)tn * 128;
    f32x4 acc[4][4] = {};
    const int nk = K / 32;
    for (int kt = 0; kt < nk; ++kt) {
        __syncthreads();
        const int k0 = kt * 32;
#pragma unroll
        for (int i = 0; i < 2; ++i) {
            const int r = i * 64 + wave * 16 + srow;
            const size_t loff = (size_t)(i * 2048 + wave * 512);
            gload_lds16(A + (rowA0 + r) * (long)K + k0 + scol, (void*)(As + loff));
            gload_lds16(W + (rowW0 + r) * (long)K + k0 + scol, (void*)(Ws + loff));
        }
        __syncthreads();
        bf16x8 af[4], wf[4];
#pragma unroll
        for (int m = 0; m < 4; ++m)
            af[m] = *(const bf16x8*)(As + (wr * 64 + m * 16 + fr) * 32 + fq * 8);
#pragma unroll
        for (int n = 0; n < 4; ++n)
            wf[n] = *(const bf16x8*)(Ws + (wc * 64 + n * 16 + fr) * 32 + fq * 8);
#pragma unroll
        for (int m = 0; m < 4; ++m)
#pragma unroll
            for (int n = 0; n < 4; ++n)
                acc[m][n] = __builtin_amdgcn_mfma_f32_16x16x32_bf16(af[m], wf[n], acc[m][n], 0, 0, 0);
    }
#pragma unroll
    for (int n = 0; n < 4; ++n) {
        const int col = tn * 128 + wc * 64 + n * 16 + fr;
        const float s = scales[col], b = bias[col];
#pragma unroll
        for (int m = 0; m < 4; ++m) {
            const int row0 = tm * 128 + wr * 64 + m * 16 + fq * 4;
#pragma unroll
            for (int j = 0; j < 4; ++j)
                C[(long)(row0 + j) * N + col] = acc[m][n][j] * s + b;
        }
    }
}

// fallback #2: fp32 (no ws / odd shapes)
__global__ __launch_bounds__(256) void gemm_fallback_kernel(
        const float* __restrict__ A, const int* __restrict__ W,
        const float* __restrict__ scales, const float* __restrict__ bias,
        float* __restrict__ C, int M, int N, int K) {
    __shared__ float As[64][16];
    __shared__ float Ws[64][16];
    const int tiles_n = N / 64;
    const int tm = blockIdx.x / tiles_n, tn = blockIdx.x % tiles_n;
    const int tid = threadIdx.x, tx = tid & 15, ty = tid >> 4;
    float acc[4][4] = {};
    for (int k0 = 0; k0 < K; k0 += 16) {
        __syncthreads();
#pragma unroll
        for (int i = 0; i < 4; ++i) {
            const int idx = tid + i * 256;
            const int r = idx >> 4, c = idx & 15;
            As[r][c] = A[(long)(tm * 64 + r) * K + k0 + c];
            Ws[r][c] = (float)W[(long)(tn * 64 + r) * K + k0 + c];
        }
        __syncthreads();
#pragma unroll
        for (int kk = 0; kk < 16; ++kk) {
            float a[4], w[4];
#pragma unroll
            for (int r = 0; r < 4; ++r) a[r] = As[ty * 4 + r][kk];
#pragma unroll
            for (int c = 0; c < 4; ++c) w[c] = Ws[tx * 4 + c][kk];
#pragma unroll
            for (int r = 0; r < 4; ++r)
#pragma unroll
                for (int c = 0; c < 4; ++c) acc[r][c] += a[r] * w[c];
        }
    }
#pragma unroll
    for (int r = 0; r < 4; ++r)
#pragma unroll
        for (int c = 0; c < 4; ++c) {
            const int col = tn * 64 + tx * 4 + c;
            C[(long)(tm * 64 + ty * 4 + r) * N + col] = acc[r][c] * scales[col] + bias[col];
        }
}

extern "C" void kernel_launch(void* const* d_in, const int* in_sizes, int n_in,
                              void* d_out, int out_size, void* d_ws, size_t ws_size,
                              hipStream_t stream) {
    const float* A32    = (const float*)d_in[0];
    const int*   Wq     = (const int*)d_in[1];
    const float* scales = (const float*)d_in[2];
    const float* bias   = (const float*)d_in[3];
    float* C = (float*)d_out;

    const long aElems = in_sizes[0];
    const long wElems = in_sizes[1];
    const int  N = in_sizes[2];
    const int  K = (int)(wElems / N);
    const int  M = (int)(aElems / K);

    const size_t need = (size_t)(aElems + wElems) * 2;
    const bool div256 = (M % 256 == 0) && (N % 256 == 0) && (K % 128 == 0);
    const bool div128 = (M % 128 == 0) && (N % 128 == 0) && (K % 32 == 0);

    if (ws_size >= need && (div256 || div128)) {
        unsigned short* Abf = (unsigned short*)d_ws;
        unsigned short* Wbf = Abf + aElems;
        cvt_f32_bf16_kernel<<<2048, 256, 0, stream>>>(A32, Abf, aElems);
        cvt_i32_bf16_kernel<<<2048, 256, 0, stream>>>(Wq, Wbf, wElems);
        if (div256) {
            const int nwg = (M / 256) * (N / 256);
            gemm_bf16_8phase<<<nwg, 512, 131072, stream>>>(Abf, Wbf, scales, bias, C, M, N, K);
        } else {
            const int nwg = (M / 128) * (N / 128);
            gemm_bf16_128<<<nwg, 256, 0, stream>>>(Abf, Wbf, scales, bias, C, M, N, K);
        }
    } else {
        const int nwg = (M / 64) * (N / 64);
        gemm_fallback_kernel<<<nwg, 256, 0, stream>>>(A32, Wq, scales, bias, C, M, N, K);
    }
}